// Round 3
// baseline (7326.620 us; speedup 1.0000x reference)
//
#include <hip/hip_runtime.h>
#include <hip/hip_bf16.h>

typedef unsigned short ushort_t;
typedef unsigned int uint_t;

#define NN    10000
#define NE    320000
#define NL    4

// ---- workspace float offsets (total 1,330,000 floats = 5.32 MB) -------------
// coord lives directly in d_out (fp32, 30000 elems, fully initialized by node_init)
#define OFF_FIELD 0        // 30000
#define OFF_CNT   30000    // 10000
#define OFF_HH    40000    // 640000
#define OFF_CSUM  680000   // 30000  (contiguous with MAGG for one memset)
#define OFF_MAGG  710000   // 640000 -> end 1350000

__device__ __forceinline__ float silu(float x) {
    return x / (1.0f + __expf(-x));
}
__device__ __forceinline__ float bf2f(ushort_t u) {
    union { uint_t x; float f; } t; t.x = ((uint_t)u) << 16; return t.f;
}
// fp32 -> bf16 with round-to-nearest-even
__device__ __forceinline__ ushort_t f2bf(float f) {
    union { float f; uint_t u; } v; v.f = f;
    const uint_t r = (v.u + 0x7FFFu + ((v.u >> 16) & 1u)) >> 16;
    return (ushort_t)r;
}

// ---- edge-degree count (once per call) --------------------------------------
__global__ __launch_bounds__(256) void count_kernel(const int* __restrict__ rows,
                                                    float* __restrict__ cnt) {
    const int e = blockIdx.x * 256 + threadIdx.x;
    if (e < NE) {
        int r = rows[e];
        r = ((uint_t)r < (uint_t)NN) ? r : 0;
        atomicAdd(&cnt[r], 1.0f);
    }
}

// ---- field network + node embedding + coord init (once per call) ------------
__global__ __launch_bounds__(256) void node_init(
    const float* __restrict__ hsrc, const float* __restrict__ xsrc,
    const float* __restrict__ vsrc, const int* __restrict__ charges,
    const float* __restrict__ cls,
    const float* __restrict__ fW1, const float* __restrict__ fb1,
    const float* __restrict__ fW2, const float* __restrict__ fb2,
    const float* __restrict__ fW3, const float* __restrict__ fb3,
    const float* __restrict__ embW, const float* __restrict__ embb,
    float* __restrict__ coord, float* __restrict__ field, float* __restrict__ hh)
{
    __shared__ float sFW1[704], sFW2[1024], sFW3[96];
    __shared__ float sFB1[32], sFB2[32], sFB3[3], sCLS[32], sEW[64], sEB[64];
    const int t = threadIdx.x;
    for (int i = t; i < 704; i += 256) sFW1[i] = fW1[i];
    for (int i = t; i < 1024; i += 256) sFW2[i] = fW2[i];
    if (t < 96) sFW3[t] = fW3[t];
    if (t < 32) { sFB1[t] = fb1[t]; sFB2[t] = fb2[t]; sCLS[t] = cls[t]; }
    if (t < 3)  sFB3[t] = fb3[t];
    if (t < 64) { sEW[t] = embW[t]; sEB[t] = embb[t]; }
    __syncthreads();

    const int n = blockIdx.x * 256 + t;
    if (n >= NN) return;

    float fin[22];
    #pragma unroll
    for (int d = 0; d < 3; d++) {
        fin[d]     = xsrc[3 * n + d];
        fin[3 + d] = vsrc[3 * n + d];
        coord[3 * n + d] = fin[d];
    }
    int ci = charges[n];
    ci = ((uint_t)ci < 2u) ? ci : 0;
    const int cix = ci * 16;
    #pragma unroll
    for (int k = 0; k < 16; k++) fin[6 + k] = sCLS[cix + k];

    float h1[32];
    #pragma unroll
    for (int j = 0; j < 32; j++) h1[j] = sFB1[j];
    #pragma unroll
    for (int k = 0; k < 22; k++) {
        const float v = fin[k];
        #pragma unroll
        for (int j = 0; j < 32; j++) h1[j] += v * sFW1[k * 32 + j];
    }
    #pragma unroll
    for (int j = 0; j < 32; j++) h1[j] = silu(h1[j]);

    float h2[32];
    #pragma unroll
    for (int j = 0; j < 32; j++) h2[j] = sFB2[j];
    #pragma unroll
    for (int k = 0; k < 32; k++) {
        const float v = h1[k];
        #pragma unroll
        for (int j = 0; j < 32; j++) h2[j] += v * sFW2[k * 32 + j];
    }
    #pragma unroll
    for (int j = 0; j < 32; j++) h2[j] = silu(h2[j]);

    #pragma unroll
    for (int d = 0; d < 3; d++) {
        float s = sFB3[d];
        #pragma unroll
        for (int j = 0; j < 32; j++) s += h2[j] * sFW3[j * 3 + d];
        field[3 * n + d] = s;
    }

    const float hv = hsrc[n];
    #pragma unroll
    for (int j = 0; j < 64; j++) hh[(size_t)n * 64 + j] = hv * sEW[j] + sEB[j];
}

// ---- per-layer edge kernel (the hot one) ------------------------------------
// LDS: W1 fp32 33536 B + W2 fp32 16384 B + cW1 bf16 8192 B + biases 1024 B
//    = 59136 B < 64 KB -> 2 blocks/CU
__global__ __launch_bounds__(256, 2) void edge_kernel(
    const int* __restrict__ rows, const int* __restrict__ cols,
    const float* __restrict__ coord, const float* __restrict__ hh,
    const float* __restrict__ eattr,
    const float* __restrict__ gEW1, const float* __restrict__ gEB1,
    const float* __restrict__ gEW2, const float* __restrict__ gEB2,
    const float* __restrict__ gCW1, const float* __restrict__ gCB1,
    const float* __restrict__ gCW2,
    float* __restrict__ csum, float* __restrict__ magg)
{
    __shared__ __align__(16) float    sW1[131 * 64];
    __shared__ __align__(16) float    sW2[64 * 64];
    __shared__ __align__(16) ushort_t sCW1[64 * 64];   // bf16 (c_W2 scale 1e-3 -> negligible)
    __shared__ float sB1[64], sB2[64], sCB1[64], sCW2v[64];

    const int t = threadIdx.x;
    for (int i = t; i < 2096; i += 256) ((float4*)sW1)[i] = ((const float4*)gEW1)[i];
    for (int i = t; i < 1024; i += 256) ((float4*)sW2)[i] = ((const float4*)gEW2)[i];
    for (int i = t; i < 4096; i += 256) sCW1[i] = f2bf(gCW1[i]);
    if (t < 64) { sB1[t] = gEB1[t]; sB2[t] = gEB2[t];
                  sCB1[t] = gCB1[t]; sCW2v[t] = gCW2[t]; }
    __syncthreads();

    for (int e = blockIdx.x * 256 + t; e < NE; e += gridDim.x * 256) {
        int r = rows[e], c = cols[e];
        r = ((uint_t)r < (uint_t)NN) ? r : 0;
        c = ((uint_t)c < (uint_t)NN) ? c : 0;
        const float dx = coord[3 * r + 0] - coord[3 * c + 0];
        const float dy = coord[3 * r + 1] - coord[3 * c + 1];
        const float dz = coord[3 * r + 2] - coord[3 * c + 2];
        const float radial = dx * dx + dy * dy + dz * dz;
        const float2 ea = ((const float2*)eattr)[e];

        float acc[64];
        #pragma unroll
        for (int j = 0; j < 64; j++) acc[j] = sB1[j];

        const float4* hr4 = (const float4*)(hh + (size_t)r * 64);
        const float4* hc4 = (const float4*)(hh + (size_t)c * 64);
        #pragma unroll 2
        for (int kk = 0; kk < 16; kk++) {
            const float4 a = hr4[kk];
            const float av[4] = {a.x, a.y, a.z, a.w};
            #pragma unroll
            for (int u = 0; u < 4; u++) {
                const float v = av[u];
                const float* w = &sW1[(kk * 4 + u) * 64];
                #pragma unroll
                for (int j = 0; j < 64; j++) acc[j] += v * w[j];
            }
        }
        #pragma unroll 2
        for (int kk = 0; kk < 16; kk++) {
            const float4 a = hc4[kk];
            const float av[4] = {a.x, a.y, a.z, a.w};
            #pragma unroll
            for (int u = 0; u < 4; u++) {
                const float v = av[u];
                const float* w = &sW1[(64 + kk * 4 + u) * 64];
                #pragma unroll
                for (int j = 0; j < 64; j++) acc[j] += v * w[j];
            }
        }
        {
            const float* w = &sW1[128 * 64];
            #pragma unroll
            for (int j = 0; j < 64; j++) acc[j] += radial * w[j];
        }
        {
            const float* w = &sW1[129 * 64];
            #pragma unroll
            for (int j = 0; j < 64; j++) acc[j] += ea.x * w[j];
        }
        {
            const float* w = &sW1[130 * 64];
            #pragma unroll
            for (int j = 0; j < 64; j++) acc[j] += ea.y * w[j];
        }
        #pragma unroll
        for (int j = 0; j < 64; j++) acc[j] = silu(acc[j]);

        float m[64];
        #pragma unroll
        for (int j = 0; j < 64; j++) m[j] = sB2[j];
        #pragma unroll
        for (int k = 0; k < 64; k++) {
            const float v = acc[k];
            const float* w = &sW2[k * 64];
            #pragma unroll
            for (int j = 0; j < 64; j++) m[j] += v * w[j];
        }
        #pragma unroll
        for (int j = 0; j < 64; j++) m[j] = silu(m[j]);

        // cw = silu(m @ cW1 + cb1) @ cW2
        float ch[64];
        #pragma unroll
        for (int j = 0; j < 64; j++) ch[j] = sCB1[j];
        #pragma unroll
        for (int k = 0; k < 64; k++) {
            const float v = m[k];
            const uint_t* w = (const uint_t*)&sCW1[k * 64];
            #pragma unroll
            for (int j2 = 0; j2 < 32; j2++) {
                const uint_t p = w[j2];
                union { uint_t u; float f; } lo, hi;
                lo.u = p << 16; hi.u = p & 0xffff0000u;
                ch[2 * j2]     += v * lo.f;
                ch[2 * j2 + 1] += v * hi.f;
            }
        }
        float cw = 0.f;
        #pragma unroll
        for (int j = 0; j < 64; j++) cw += silu(ch[j]) * sCW2v[j];

        float* cs = csum + 3 * r;
        atomicAdd(cs + 0, dx * cw);
        atomicAdd(cs + 1, dy * cw);
        atomicAdd(cs + 2, dz * cw);
        float* mg = magg + (size_t)r * 64;
        #pragma unroll
        for (int j = 0; j < 64; j++) atomicAdd(mg + j, m[j]);
    }
}

// ---- per-layer node kernel ---------------------------------------------------
// LDS: nW1 fp32 32 KB + nW2 fp32 16 KB + biases -> 49 KB. v/g weights are
// wave-uniform global reads (L1 broadcast; node kernel is latency-bound anyway).
__global__ __launch_bounds__(256, 2) void node_kernel(
    const float* __restrict__ gVW1, const float* __restrict__ gVB1,
    const float* __restrict__ gVW2, const float* __restrict__ gVB2,
    const float* __restrict__ gGW1, const float* __restrict__ gGB1,
    const float* __restrict__ gGW2, const float* __restrict__ gGB2,
    const float* __restrict__ gNW1, const float* __restrict__ gNB1,
    const float* __restrict__ gNW2, const float* __restrict__ gNB2,
    const float* __restrict__ csum, const float* __restrict__ cnt,
    const float* __restrict__ vsrc, const float* __restrict__ field,
    const float* __restrict__ magg,
    float* __restrict__ coord, float* __restrict__ hh)
{
    __shared__ __align__(16) float sNW1[128 * 64];
    __shared__ __align__(16) float sNW2[64 * 64];
    __shared__ float sNB1[64], sNB2[64];

    const int t = threadIdx.x;
    for (int i = t; i < 2048; i += 256) ((float4*)sNW1)[i] = ((const float4*)gNW1)[i];
    for (int i = t; i < 1024; i += 256) ((float4*)sNW2)[i] = ((const float4*)gNW2)[i];
    if (t < 64) { sNB1[t] = gNB1[t]; sNB2[t] = gNB2[t]; }
    __syncthreads();

    const int n = blockIdx.x * 256 + t;
    if (n >= NN) return;
    const float4* hh4 = (const float4*)(hh + (size_t)n * 64);

    // vw / gw gates (wave-uniform weight reads from global)
    float a[64], b[64];
    #pragma unroll
    for (int j = 0; j < 64; j++) { a[j] = gVB1[j]; b[j] = gGB1[j]; }
    #pragma unroll 1
    for (int kk = 0; kk < 16; kk++) {
        const float4 h4 = hh4[kk];
        const float av[4] = {h4.x, h4.y, h4.z, h4.w};
        #pragma unroll
        for (int u = 0; u < 4; u++) {
            const float v = av[u];
            const int k = kk * 4 + u;
            #pragma unroll
            for (int j = 0; j < 64; j++) {
                a[j] += v * gVW1[k * 64 + j];
                b[j] += v * gGW1[k * 64 + j];
            }
        }
    }
    float vw = gVB2[0], gw = gGB2[0];
    #pragma unroll
    for (int k = 0; k < 64; k++) { vw += silu(a[k]) * gVW2[k]; gw += silu(b[k]) * gGW2[k]; }

    const float cn = fmaxf(cnt[n], 1.0f);
    #pragma unroll
    for (int d = 0; d < 3; d++)
        coord[3 * n + d] += csum[3 * n + d] / cn
                          + vw * vsrc[3 * n + d]
                          + gw * field[3 * n + d];

    // node mlp: hh = silu([hh, magg] @ nW1 + nb1) @ nW2 + nb2
    #pragma unroll
    for (int j = 0; j < 64; j++) a[j] = sNB1[j];
    #pragma unroll 1
    for (int kk = 0; kk < 16; kk++) {
        const float4 h4 = hh4[kk];
        const float av[4] = {h4.x, h4.y, h4.z, h4.w};
        #pragma unroll
        for (int u = 0; u < 4; u++) {
            const float v = av[u];
            const float* w = &sNW1[(kk * 4 + u) * 64];
            #pragma unroll
            for (int j = 0; j < 64; j++) a[j] += v * w[j];
        }
    }
    const float4* mg4 = (const float4*)(magg + (size_t)n * 64);
    #pragma unroll 1
    for (int kk = 0; kk < 16; kk++) {
        const float4 m4 = mg4[kk];
        const float av[4] = {m4.x, m4.y, m4.z, m4.w};
        #pragma unroll
        for (int u = 0; u < 4; u++) {
            const float v = av[u];
            const float* w = &sNW1[(64 + kk * 4 + u) * 64];
            #pragma unroll
            for (int j = 0; j < 64; j++) a[j] += v * w[j];
        }
    }
    #pragma unroll
    for (int k = 0; k < 64; k++) a[k] = silu(a[k]);

    float o[64];
    #pragma unroll
    for (int j = 0; j < 64; j++) o[j] = sNB2[j];
    #pragma unroll 1
    for (int k = 0; k < 64; k++) {
        const float v = a[k];
        const float* w = &sNW2[k * 64];
        #pragma unroll
        for (int j = 0; j < 64; j++) o[j] += v * w[j];
    }
    #pragma unroll
    for (int j = 0; j < 64; j++) hh[(size_t)n * 64 + j] = o[j];
}

// ---- host launch -------------------------------------------------------------
extern "C" void kernel_launch(void* const* d_in, const int* in_sizes, int n_in,
                              void* d_out, int out_size, void* d_ws, size_t ws_size,
                              hipStream_t stream) {
    float* wsf = (float*)d_ws;
    float* coord = (float*)d_out;          // fp32 coord state lives in d_out
    const int* edges = (const int*)d_in[4];
    const int* rows = edges;
    const int* cols = edges + NE;

    hipMemsetAsync(wsf + OFF_CNT, 0, NN * sizeof(float), stream);
    count_kernel<<<(NE + 255) / 256, 256, 0, stream>>>(rows, wsf + OFF_CNT);

    node_init<<<(NN + 255) / 256, 256, 0, stream>>>(
        (const float*)d_in[0], (const float*)d_in[1], (const float*)d_in[2],
        (const int*)d_in[5], (const float*)d_in[8],
        (const float*)d_in[9],  (const float*)d_in[10],
        (const float*)d_in[11], (const float*)d_in[12],
        (const float*)d_in[13], (const float*)d_in[14],
        (const float*)d_in[6],  (const float*)d_in[7],
        coord, wsf + OFF_FIELD, wsf + OFF_HH);

    for (int l = 0; l < NL; l++) {
        hipMemsetAsync(wsf + OFF_CSUM, 0, (30000 + 640000) * sizeof(float), stream);
        edge_kernel<<<512, 256, 0, stream>>>(
            rows, cols, coord, wsf + OFF_HH, (const float*)d_in[3],
            ((const float*)d_in[15]) + l * 8384, ((const float*)d_in[16]) + l * 64,
            ((const float*)d_in[17]) + l * 4096, ((const float*)d_in[18]) + l * 64,
            ((const float*)d_in[23]) + l * 4096, ((const float*)d_in[24]) + l * 64,
            ((const float*)d_in[25]) + l * 64,
            wsf + OFF_CSUM, wsf + OFF_MAGG);
        node_kernel<<<(NN + 255) / 256, 256, 0, stream>>>(
            ((const float*)d_in[26]) + l * 4096, ((const float*)d_in[27]) + l * 64,
            ((const float*)d_in[28]) + l * 64,   ((const float*)d_in[29]) + l,
            ((const float*)d_in[30]) + l * 4096, ((const float*)d_in[31]) + l * 64,
            ((const float*)d_in[32]) + l * 64,   ((const float*)d_in[33]) + l,
            ((const float*)d_in[19]) + l * 8192, ((const float*)d_in[20]) + l * 64,
            ((const float*)d_in[21]) + l * 4096, ((const float*)d_in[22]) + l * 64,
            wsf + OFF_CSUM, wsf + OFF_CNT, (const float*)d_in[2],
            wsf + OFF_FIELD, wsf + OFF_MAGG, coord, wsf + OFF_HH);
    }
}

// Round 4
// 3423.331 us; speedup vs baseline: 2.1402x; 2.1402x over previous
//
#include <hip/hip_runtime.h>
#include <hip/hip_bf16.h>

typedef unsigned short ushort_t;
typedef unsigned int uint_t;

#define NN    10000
#define NE    320000
#define NL    4
#define NBLK  1250      // NE / 256 exactly

// ---- workspace float offsets -------------------------------------------------
// coord lives directly in d_out (fp32, 30000 elems, fully initialized by node_init)
#define OFF_FIELD 0        // 30000
#define OFF_HH    30000    // 640000
#define OFF_CSUM  670000   // 30000  (contiguous with MAGG for one memset)
#define OFF_MAGG  700000   // 640000 -> float end 1340000
// ---- int region (starts at float offset 1340000) ----------------------------
#define IOFF_CNTI   0        // 10000
#define IOFF_OFF    10000    // 10001
#define IOFF_CURSOR 20001    // 10000
#define IOFF_PERM   30001    // 320000 -> int end 350001 (total ws ~6.76 MB)

__device__ __forceinline__ float silu(float x) {
    return x / (1.0f + __expf(-x));
}
// fp32 -> bf16 round-to-nearest-even
__device__ __forceinline__ ushort_t f2bf(float f) {
    union { float f; uint_t u; } v; v.f = f;
    const uint_t r = (v.u + 0x7FFFu + ((v.u >> 16) & 1u)) >> 16;
    return (ushort_t)r;
}
__device__ __forceinline__ void unpack2(uint_t p, float& lo, float& hi) {
    union { uint_t u; float f; } a, b;
    a.u = p << 16; b.u = p & 0xffff0000u;
    lo = a.f; hi = b.f;
}

// ---- CSR build: per-row int counts ------------------------------------------
__global__ __launch_bounds__(256) void counti_kernel(const int* __restrict__ rows,
                                                     int* __restrict__ cnti) {
    const int e = blockIdx.x * 256 + threadIdx.x;
    if (e < NE) {
        int r = rows[e];
        r = ((uint_t)r < (uint_t)NN) ? r : 0;
        atomicAdd(&cnti[r], 1);
    }
}

// ---- CSR build: exclusive scan over 10000 counts (single block) --------------
__global__ __launch_bounds__(1024) void scan_kernel(const int* __restrict__ cnti,
                                                    int* __restrict__ off,
                                                    int* __restrict__ cursor) {
    __shared__ int part[1024];
    const int t = threadIdx.x;
    const int base = t * 10;
    int loc[10];
    int s = 0;
    #pragma unroll
    for (int i = 0; i < 10; i++) {
        const int idx = base + i;
        const int v = (idx < NN) ? cnti[idx] : 0;
        loc[i] = s; s += v;
    }
    part[t] = s;
    __syncthreads();
    const int own = s;
    for (int d = 1; d < 1024; d <<= 1) {
        const int v = (t >= d) ? part[t - d] : 0;
        __syncthreads();
        part[t] += v;
        __syncthreads();
    }
    const int excl = part[t] - own;
    #pragma unroll
    for (int i = 0; i < 10; i++) {
        const int idx = base + i;
        if (idx < NN) { const int o = excl + loc[i]; off[idx] = o; cursor[idx] = o; }
    }
    if (t == 0) off[NN] = NE;
}

// ---- CSR build: scatter edge ids into row-sorted order -----------------------
__global__ __launch_bounds__(256) void scatter_kernel(const int* __restrict__ rows,
                                                      int* __restrict__ cursor,
                                                      int* __restrict__ perm) {
    const int e = blockIdx.x * 256 + threadIdx.x;
    if (e < NE) {
        int r = rows[e];
        r = ((uint_t)r < (uint_t)NN) ? r : 0;
        const int pos = atomicAdd(&cursor[r], 1);
        if ((uint_t)pos < (uint_t)NE) perm[pos] = e;
    }
}

// ---- field network + node embedding + coord init (once per call) ------------
__global__ __launch_bounds__(256) void node_init(
    const float* __restrict__ hsrc, const float* __restrict__ xsrc,
    const float* __restrict__ vsrc, const int* __restrict__ charges,
    const float* __restrict__ cls,
    const float* __restrict__ fW1, const float* __restrict__ fb1,
    const float* __restrict__ fW2, const float* __restrict__ fb2,
    const float* __restrict__ fW3, const float* __restrict__ fb3,
    const float* __restrict__ embW, const float* __restrict__ embb,
    float* __restrict__ coord, float* __restrict__ field, float* __restrict__ hh)
{
    __shared__ float sFW1[704], sFW2[1024], sFW3[96];
    __shared__ float sFB1[32], sFB2[32], sFB3[3], sCLS[32], sEW[64], sEB[64];
    const int t = threadIdx.x;
    for (int i = t; i < 704; i += 256) sFW1[i] = fW1[i];
    for (int i = t; i < 1024; i += 256) sFW2[i] = fW2[i];
    if (t < 96) sFW3[t] = fW3[t];
    if (t < 32) { sFB1[t] = fb1[t]; sFB2[t] = fb2[t]; sCLS[t] = cls[t]; }
    if (t < 3)  sFB3[t] = fb3[t];
    if (t < 64) { sEW[t] = embW[t]; sEB[t] = embb[t]; }
    __syncthreads();

    const int n = blockIdx.x * 256 + t;
    if (n >= NN) return;

    float fin[22];
    #pragma unroll
    for (int d = 0; d < 3; d++) {
        fin[d]     = xsrc[3 * n + d];
        fin[3 + d] = vsrc[3 * n + d];
        coord[3 * n + d] = fin[d];
    }
    int ci = charges[n];
    ci = ((uint_t)ci < 2u) ? ci : 0;
    const int cix = ci * 16;
    #pragma unroll
    for (int k = 0; k < 16; k++) fin[6 + k] = sCLS[cix + k];

    float h1[32];
    #pragma unroll
    for (int j = 0; j < 32; j++) h1[j] = sFB1[j];
    #pragma unroll
    for (int k = 0; k < 22; k++) {
        const float v = fin[k];
        #pragma unroll
        for (int j = 0; j < 32; j++) h1[j] += v * sFW1[k * 32 + j];
    }
    #pragma unroll
    for (int j = 0; j < 32; j++) h1[j] = silu(h1[j]);

    float h2[32];
    #pragma unroll
    for (int j = 0; j < 32; j++) h2[j] = sFB2[j];
    #pragma unroll
    for (int k = 0; k < 32; k++) {
        const float v = h1[k];
        #pragma unroll
        for (int j = 0; j < 32; j++) h2[j] += v * sFW2[k * 32 + j];
    }
    #pragma unroll
    for (int j = 0; j < 32; j++) h2[j] = silu(h2[j]);

    #pragma unroll
    for (int d = 0; d < 3; d++) {
        float s = sFB3[d];
        #pragma unroll
        for (int j = 0; j < 32; j++) s += h2[j] * sFW3[j * 3 + d];
        field[3 * n + d] = s;
    }

    const float hv = hsrc[n];
    #pragma unroll
    for (int j = 0; j < 64; j++) hh[(size_t)n * 64 + j] = hv * sEW[j] + sEB[j];
}

// ---- per-layer edge kernel: sorted edges + LDS segmented reduction -----------
// LDS: sW1 bf16 16768 + sW2 fp32 16384 + sCW1 bf16 8192 + biases 1024
//    + tile 16384 + srow 1024 + sscan 1024 + segstart 1028 + snseg 4 = 62832 B
__global__ __launch_bounds__(256, 2) void edge_kernel(
    const int* __restrict__ rows, const int* __restrict__ cols,
    const int* __restrict__ perm,
    const float* __restrict__ coord, const float* __restrict__ hh,
    const float* __restrict__ eattr,
    const float* __restrict__ gEW1, const float* __restrict__ gEB1,
    const float* __restrict__ gEW2, const float* __restrict__ gEB2,
    const float* __restrict__ gCW1, const float* __restrict__ gCB1,
    const float* __restrict__ gCW2,
    float* __restrict__ csum, float* __restrict__ magg)
{
    __shared__ __align__(16) ushort_t sW1[131 * 64];   // bf16
    __shared__ __align__(16) float    sW2[64 * 64];    // fp32
    __shared__ __align__(16) ushort_t sCW1[64 * 64];   // bf16
    __shared__ float sB1[64], sB2[64], sCB1[64], sCW2v[64];
    __shared__ float tile[256 * 16];
    __shared__ int   srow[256];
    __shared__ int   sscan[256];
    __shared__ int   segstart[257];
    __shared__ int   snseg;

    const int t = threadIdx.x;
    for (int i = t; i < 2096; i += 256) {          // 131*64 = 8384 = 2096 float4
        const float4 v = ((const float4*)gEW1)[i];
        sW1[4 * i + 0] = f2bf(v.x); sW1[4 * i + 1] = f2bf(v.y);
        sW1[4 * i + 2] = f2bf(v.z); sW1[4 * i + 3] = f2bf(v.w);
    }
    for (int i = t; i < 1024; i += 256) ((float4*)sW2)[i] = ((const float4*)gEW2)[i];
    for (int i = t; i < 1024; i += 256) {          // 64*64 = 4096 = 1024 float4
        const float4 v = ((const float4*)gCW1)[i];
        sCW1[4 * i + 0] = f2bf(v.x); sCW1[4 * i + 1] = f2bf(v.y);
        sCW1[4 * i + 2] = f2bf(v.z); sCW1[4 * i + 3] = f2bf(v.w);
    }
    if (t < 64) { sB1[t] = gEB1[t]; sB2[t] = gEB2[t];
                  sCB1[t] = gCB1[t]; sCW2v[t] = gCW2[t]; }

    const int ep = blockIdx.x * 256 + t;           // NE = 1250*256 exactly, no tail
    int e = perm[ep];
    e = ((uint_t)e < (uint_t)NE) ? e : 0;
    int r = rows[e], c = cols[e];
    r = ((uint_t)r < (uint_t)NN) ? r : 0;
    c = ((uint_t)c < (uint_t)NN) ? c : 0;
    srow[t] = r;
    __syncthreads();

    // block-level segment boundaries over sorted rows
    const int flag = (t == 0) ? 1 : ((srow[t] != srow[t - 1]) ? 1 : 0);
    sscan[t] = flag;
    __syncthreads();
    for (int d = 1; d < 256; d <<= 1) {
        const int v = (t >= d) ? sscan[t - d] : 0;
        __syncthreads();
        sscan[t] += v;
        __syncthreads();
    }
    const int lr = sscan[t] - 1;
    if (flag) segstart[lr] = t;
    if (t == 255) snseg = sscan[255];
    __syncthreads();
    const int nseg = snseg;
    if (t == 0) segstart[nseg] = 256;
    // (next __syncthreads before tile use covers this write)

    // ---- edge MLP ----
    const float dx = coord[3 * r + 0] - coord[3 * c + 0];
    const float dy = coord[3 * r + 1] - coord[3 * c + 1];
    const float dz = coord[3 * r + 2] - coord[3 * c + 2];
    const float radial = dx * dx + dy * dy + dz * dz;
    const float2 ea = ((const float2*)eattr)[e];

    float acc[64];
    #pragma unroll
    for (int j = 0; j < 64; j++) acc[j] = sB1[j];

    const float4* hr4 = (const float4*)(hh + (size_t)r * 64);
    const float4* hc4 = (const float4*)(hh + (size_t)c * 64);
    #pragma unroll 2
    for (int kk = 0; kk < 16; kk++) {
        const float4 a = hr4[kk];
        const float av[4] = {a.x, a.y, a.z, a.w};
        #pragma unroll
        for (int u = 0; u < 4; u++) {
            const float v = av[u];
            const uint_t* w = (const uint_t*)&sW1[(kk * 4 + u) * 64];
            #pragma unroll
            for (int j2 = 0; j2 < 32; j2++) {
                float lo, hi; unpack2(w[j2], lo, hi);
                acc[2 * j2]     += v * lo;
                acc[2 * j2 + 1] += v * hi;
            }
        }
    }
    #pragma unroll 2
    for (int kk = 0; kk < 16; kk++) {
        const float4 a = hc4[kk];
        const float av[4] = {a.x, a.y, a.z, a.w};
        #pragma unroll
        for (int u = 0; u < 4; u++) {
            const float v = av[u];
            const uint_t* w = (const uint_t*)&sW1[(64 + kk * 4 + u) * 64];
            #pragma unroll
            for (int j2 = 0; j2 < 32; j2++) {
                float lo, hi; unpack2(w[j2], lo, hi);
                acc[2 * j2]     += v * lo;
                acc[2 * j2 + 1] += v * hi;
            }
        }
    }
    {
        const float ext[3] = {radial, ea.x, ea.y};
        #pragma unroll
        for (int x = 0; x < 3; x++) {
            const float v = ext[x];
            const uint_t* w = (const uint_t*)&sW1[(128 + x) * 64];
            #pragma unroll
            for (int j2 = 0; j2 < 32; j2++) {
                float lo, hi; unpack2(w[j2], lo, hi);
                acc[2 * j2]     += v * lo;
                acc[2 * j2 + 1] += v * hi;
            }
        }
    }
    #pragma unroll
    for (int j = 0; j < 64; j++) acc[j] = silu(acc[j]);

    float m[64];
    #pragma unroll
    for (int j = 0; j < 64; j++) m[j] = sB2[j];
    #pragma unroll
    for (int k = 0; k < 64; k++) {
        const float v = acc[k];
        const float* w = &sW2[k * 64];
        #pragma unroll
        for (int j = 0; j < 64; j++) m[j] += v * w[j];
    }
    #pragma unroll
    for (int j = 0; j < 64; j++) m[j] = silu(m[j]);

    // cw = silu(m @ cW1 + cb1) @ cW2
    float ch[64];
    #pragma unroll
    for (int j = 0; j < 64; j++) ch[j] = sCB1[j];
    #pragma unroll
    for (int k = 0; k < 64; k++) {
        const float v = m[k];
        const uint_t* w = (const uint_t*)&sCW1[k * 64];
        #pragma unroll
        for (int j2 = 0; j2 < 32; j2++) {
            float lo, hi; unpack2(w[j2], lo, hi);
            ch[2 * j2]     += v * lo;
            ch[2 * j2 + 1] += v * hi;
        }
    }
    float cw = 0.f;
    #pragma unroll
    for (int j = 0; j < 64; j++) cw += silu(ch[j]) * sCW2v[j];

    // ---- segmented reduction: magg (4 chunks of 16 channels) ----
    for (int ch0 = 0; ch0 < 64; ch0 += 16) {
        __syncthreads();
        #pragma unroll
        for (int cc = 0; cc < 16; cc++) tile[t * 16 + cc] = m[ch0 + cc];
        __syncthreads();
        for (int w = t; w < nseg * 16; w += 256) {
            const int lr2 = w >> 4, cc = w & 15;
            const int p0 = segstart[lr2], p1 = segstart[lr2 + 1];
            float s = 0.f;
            for (int p = p0; p < p1; p++) s += tile[p * 16 + cc];
            atomicAdd(&magg[(size_t)srow[p0] * 64 + ch0 + cc], s);
        }
    }

    // ---- segmented reduction: csum (3 channels) ----
    __syncthreads();
    tile[t * 16 + 0] = dx * cw;
    tile[t * 16 + 1] = dy * cw;
    tile[t * 16 + 2] = dz * cw;
    __syncthreads();
    for (int w = t; w < nseg * 3; w += 256) {
        const int lr2 = w / 3, cc = w - lr2 * 3;
        const int p0 = segstart[lr2], p1 = segstart[lr2 + 1];
        float s = 0.f;
        for (int p = p0; p < p1; p++) s += tile[p * 16 + cc];
        atomicAdd(&csum[3 * srow[p0] + cc], s);
    }
}

// ---- per-layer node kernel (unchanged except cnt from CSR offsets) -----------
__global__ __launch_bounds__(256, 2) void node_kernel(
    const float* __restrict__ gVW1, const float* __restrict__ gVB1,
    const float* __restrict__ gVW2, const float* __restrict__ gVB2,
    const float* __restrict__ gGW1, const float* __restrict__ gGB1,
    const float* __restrict__ gGW2, const float* __restrict__ gGB2,
    const float* __restrict__ gNW1, const float* __restrict__ gNB1,
    const float* __restrict__ gNW2, const float* __restrict__ gNB2,
    const float* __restrict__ csum, const int* __restrict__ off,
    const float* __restrict__ vsrc, const float* __restrict__ field,
    const float* __restrict__ magg,
    float* __restrict__ coord, float* __restrict__ hh)
{
    __shared__ __align__(16) float sNW1[128 * 64];
    __shared__ __align__(16) float sNW2[64 * 64];
    __shared__ float sNB1[64], sNB2[64];

    const int t = threadIdx.x;
    for (int i = t; i < 2048; i += 256) ((float4*)sNW1)[i] = ((const float4*)gNW1)[i];
    for (int i = t; i < 1024; i += 256) ((float4*)sNW2)[i] = ((const float4*)gNW2)[i];
    if (t < 64) { sNB1[t] = gNB1[t]; sNB2[t] = gNB2[t]; }
    __syncthreads();

    const int n = blockIdx.x * 256 + t;
    if (n >= NN) return;
    const float4* hh4 = (const float4*)(hh + (size_t)n * 64);

    float a[64], b[64];
    #pragma unroll
    for (int j = 0; j < 64; j++) { a[j] = gVB1[j]; b[j] = gGB1[j]; }
    #pragma unroll 1
    for (int kk = 0; kk < 16; kk++) {
        const float4 h4 = hh4[kk];
        const float av[4] = {h4.x, h4.y, h4.z, h4.w};
        #pragma unroll
        for (int u = 0; u < 4; u++) {
            const float v = av[u];
            const int k = kk * 4 + u;
            #pragma unroll
            for (int j = 0; j < 64; j++) {
                a[j] += v * gVW1[k * 64 + j];
                b[j] += v * gGW1[k * 64 + j];
            }
        }
    }
    float vw = gVB2[0], gw = gGB2[0];
    #pragma unroll
    for (int k = 0; k < 64; k++) { vw += silu(a[k]) * gVW2[k]; gw += silu(b[k]) * gGW2[k]; }

    const float cn = fmaxf((float)(off[n + 1] - off[n]), 1.0f);
    #pragma unroll
    for (int d = 0; d < 3; d++)
        coord[3 * n + d] += csum[3 * n + d] / cn
                          + vw * vsrc[3 * n + d]
                          + gw * field[3 * n + d];

    #pragma unroll
    for (int j = 0; j < 64; j++) a[j] = sNB1[j];
    #pragma unroll 1
    for (int kk = 0; kk < 16; kk++) {
        const float4 h4 = hh4[kk];
        const float av[4] = {h4.x, h4.y, h4.z, h4.w};
        #pragma unroll
        for (int u = 0; u < 4; u++) {
            const float v = av[u];
            const float* w = &sNW1[(kk * 4 + u) * 64];
            #pragma unroll
            for (int j = 0; j < 64; j++) a[j] += v * w[j];
        }
    }
    const float4* mg4 = (const float4*)(magg + (size_t)n * 64);
    #pragma unroll 1
    for (int kk = 0; kk < 16; kk++) {
        const float4 m4 = mg4[kk];
        const float av[4] = {m4.x, m4.y, m4.z, m4.w};
        #pragma unroll
        for (int u = 0; u < 4; u++) {
            const float v = av[u];
            const float* w = &sNW1[(64 + kk * 4 + u) * 64];
            #pragma unroll
            for (int j = 0; j < 64; j++) a[j] += v * w[j];
        }
    }
    #pragma unroll
    for (int k = 0; k < 64; k++) a[k] = silu(a[k]);

    float o[64];
    #pragma unroll
    for (int j = 0; j < 64; j++) o[j] = sNB2[j];
    #pragma unroll 1
    for (int k = 0; k < 64; k++) {
        const float v = a[k];
        const float* w = &sNW2[k * 64];
        #pragma unroll
        for (int j = 0; j < 64; j++) o[j] += v * w[j];
    }
    #pragma unroll
    for (int j = 0; j < 64; j++) hh[(size_t)n * 64 + j] = o[j];
}

// ---- host launch -------------------------------------------------------------
extern "C" void kernel_launch(void* const* d_in, const int* in_sizes, int n_in,
                              void* d_out, int out_size, void* d_ws, size_t ws_size,
                              hipStream_t stream) {
    float* wsf = (float*)d_ws;
    int*   wsi = (int*)(wsf + 1340000);
    float* coord = (float*)d_out;          // fp32 coord state lives in d_out
    const int* edges = (const int*)d_in[4];
    const int* rows = edges;
    const int* cols = edges + NE;

    // ---- CSR build (once per call) ----
    hipMemsetAsync(wsi + IOFF_CNTI, 0, NN * sizeof(int), stream);
    counti_kernel<<<(NE + 255) / 256, 256, 0, stream>>>(rows, wsi + IOFF_CNTI);
    scan_kernel<<<1, 1024, 0, stream>>>(wsi + IOFF_CNTI, wsi + IOFF_OFF, wsi + IOFF_CURSOR);
    scatter_kernel<<<(NE + 255) / 256, 256, 0, stream>>>(rows, wsi + IOFF_CURSOR,
                                                         wsi + IOFF_PERM);

    node_init<<<(NN + 255) / 256, 256, 0, stream>>>(
        (const float*)d_in[0], (const float*)d_in[1], (const float*)d_in[2],
        (const int*)d_in[5], (const float*)d_in[8],
        (const float*)d_in[9],  (const float*)d_in[10],
        (const float*)d_in[11], (const float*)d_in[12],
        (const float*)d_in[13], (const float*)d_in[14],
        (const float*)d_in[6],  (const float*)d_in[7],
        coord, wsf + OFF_FIELD, wsf + OFF_HH);

    for (int l = 0; l < NL; l++) {
        hipMemsetAsync(wsf + OFF_CSUM, 0, (30000 + 640000) * sizeof(float), stream);
        edge_kernel<<<NBLK, 256, 0, stream>>>(
            rows, cols, wsi + IOFF_PERM,
            coord, wsf + OFF_HH, (const float*)d_in[3],
            ((const float*)d_in[15]) + l * 8384, ((const float*)d_in[16]) + l * 64,
            ((const float*)d_in[17]) + l * 4096, ((const float*)d_in[18]) + l * 64,
            ((const float*)d_in[23]) + l * 4096, ((const float*)d_in[24]) + l * 64,
            ((const float*)d_in[25]) + l * 64,
            wsf + OFF_CSUM, wsf + OFF_MAGG);
        node_kernel<<<(NN + 255) / 256, 256, 0, stream>>>(
            ((const float*)d_in[26]) + l * 4096, ((const float*)d_in[27]) + l * 64,
            ((const float*)d_in[28]) + l * 64,   ((const float*)d_in[29]) + l,
            ((const float*)d_in[30]) + l * 4096, ((const float*)d_in[31]) + l * 64,
            ((const float*)d_in[32]) + l * 64,   ((const float*)d_in[33]) + l,
            ((const float*)d_in[19]) + l * 8192, ((const float*)d_in[20]) + l * 64,
            ((const float*)d_in[21]) + l * 4096, ((const float*)d_in[22]) + l * 64,
            wsf + OFF_CSUM, wsi + IOFF_OFF, (const float*)d_in[2],
            wsf + OFF_FIELD, wsf + OFF_MAGG, coord, wsf + OFF_HH);
    }
}